// Round 1
// 420.257 us; speedup vs baseline: 1.0986x; 1.0986x over previous
//
#include <hip/hip_runtime.h>
#include <math.h>

typedef unsigned short ushort_t;
typedef unsigned int uint_t;
typedef __attribute__((ext_vector_type(8))) short short8;
typedef __attribute__((ext_vector_type(4))) float fx4;

__device__ __forceinline__ float bf16_to_f32(ushort_t u) {
    union { uint_t i; float f; } c;
    c.i = ((uint_t)u) << 16;
    return c.f;
}
__device__ __forceinline__ ushort_t f32_to_bf16(float f) {
    union { float f; uint_t i; } c;
    c.f = f;
    const uint_t x = c.i;
    return (ushort_t)((x + 0x7fffu + ((x >> 16) & 1u)) >> 16);
}

// ---- W transpose + bf16 convert: WT[m][k] = bf16(W[k][m]) ----------------
__global__ void convT_kernel(const float* __restrict__ W,
                             ushort_t* __restrict__ WT, int k, int m) {
    const int idx = blockIdx.x * 256 + threadIdx.x;
    if (idx >= k * m) return;
    const int mm = idx / k;
    const int kk = idx % k;
    WT[idx] = f32_to_bf16(W[(size_t)kk * m + mm]);
}

// ---- MFMA GEMM with B staged in LDS ---------------------------------------
// C[n][TILES*16](bf16) = A[n][K] * B[K][TILES*16], BT[col][K] bf16.
// 4 waves/block, each wave owns 2 row-tiles (32 rows) -> block = 128 rows.
// BT (whole B panel, 64KB/16KB) staged in LDS once, XOR-swizzled on 16B
// chunks (c ^ (row&7)) so stride-K ds_read_b128 is <=2-way conflicted (free).
// A is register double-buffered: prefetch kc+1 while MFMAing kc.
// Fragment maps (gfx950, verified): A: m=lane&15, k=quad*8+j;
// B: n=lane&15, k=quad*8+j; C/D: col=lane&15, row=quad*4+reg.
template <int TILES, bool A_F32, int K>
__global__ __launch_bounds__(256) void gemm_lds_kernel(
    const void* __restrict__ Avoid, const ushort_t* __restrict__ BT,
    ushort_t* __restrict__ C, int n) {
    constexpr int M = TILES * 16;
    constexpr int CH = K / 8;  // 16B chunks per B row
    constexpr int NC = K / 32; // K-chunks
    __shared__ ushort_t lds[M * K];  // 64KB (layer1) / 16KB (layer2)
    const int tid = threadIdx.x;

    // ---- stage BT -> LDS, swizzled ----
#pragma unroll
    for (int i = 0; i < (M * CH + 255) / 256; ++i) {
        const int idx = tid + i * 256;
        if (idx < M * CH) {
            const int row = idx / CH;
            const int c = idx - row * CH;
            *(short8*)&lds[(size_t)(row * CH + (c ^ (row & 7))) * 8] =
                *(const short8*)(BT + (size_t)row * K + c * 8);
        }
    }
    __syncthreads();

    const int wave = tid >> 6;
    const int lane = tid & 63;
    const int l15 = lane & 15;
    const int quad = lane >> 4;
    const int rowbase = blockIdx.x * 128 + wave * 32;
    const int r0 = min(rowbase + l15, n - 1);
    const int r1 = min(rowbase + 16 + l15, n - 1);
    const size_t off0 = (size_t)r0 * K + quad * 8;
    const size_t off1 = (size_t)r1 * K + quad * 8;

    fx4 acc[2][TILES];
#pragma unroll
    for (int rp = 0; rp < 2; ++rp)
#pragma unroll
        for (int t = 0; t < TILES; ++t) acc[rp][t] = (fx4){0.f, 0.f, 0.f, 0.f};

    // A register double-buffer
    fx4 c0a, c0b, c1a, c1b, n0a, n0b, n1a, n1b;
    short8 cb0, cb1, nb0, nb1;

    if constexpr (A_F32) {
        const float* A = (const float*)Avoid;
        c0a = *(const fx4*)(A + off0);
        c0b = *(const fx4*)(A + off0 + 4);
        c1a = *(const fx4*)(A + off1);
        c1b = *(const fx4*)(A + off1 + 4);
    } else {
        const ushort_t* A = (const ushort_t*)Avoid;
        cb0 = *(const short8*)(A + off0);
        cb1 = *(const short8*)(A + off1);
    }

#pragma unroll
    for (int kc = 0; kc < NC; ++kc) {
        // prefetch next K-chunk of A (independent of this chunk's MFMAs)
        if (kc + 1 < NC) {
            const int kd = (kc + 1) * 32;
            if constexpr (A_F32) {
                const float* A = (const float*)Avoid;
                n0a = *(const fx4*)(A + off0 + kd);
                n0b = *(const fx4*)(A + off0 + kd + 4);
                n1a = *(const fx4*)(A + off1 + kd);
                n1b = *(const fx4*)(A + off1 + kd + 4);
            } else {
                const ushort_t* A = (const ushort_t*)Avoid;
                nb0 = *(const short8*)(A + off0 + kd);
                nb1 = *(const short8*)(A + off1 + kd);
            }
        }
        // B fragments from LDS (shared by both row-tiles)
        short8 bf[TILES];
#pragma unroll
        for (int t = 0; t < TILES; ++t) {
            const int brow = t * 16 + l15;
            const int c = kc * 4 + quad;
            bf[t] = *(const short8*)&lds[(size_t)(brow * CH +
                                                  (c ^ (brow & 7))) * 8];
        }
        // A fragments (convert f32 path)
        short8 af0, af1;
        if constexpr (A_F32) {
            union { short8 v; ushort_t u[8]; } u0, u1;
#pragma unroll
            for (int j = 0; j < 4; ++j) {
                u0.u[j] = f32_to_bf16(c0a[j]);
                u0.u[4 + j] = f32_to_bf16(c0b[j]);
                u1.u[j] = f32_to_bf16(c1a[j]);
                u1.u[4 + j] = f32_to_bf16(c1b[j]);
            }
            af0 = u0.v;
            af1 = u1.v;
        } else {
            af0 = cb0;
            af1 = cb1;
        }
#pragma unroll
        for (int t = 0; t < TILES; ++t) {
            acc[0][t] = __builtin_amdgcn_mfma_f32_16x16x32_bf16(af0, bf[t],
                                                                acc[0][t],
                                                                0, 0, 0);
            acc[1][t] = __builtin_amdgcn_mfma_f32_16x16x32_bf16(af1, bf[t],
                                                                acc[1][t],
                                                                0, 0, 0);
        }
        // rotate double-buffer (static, unrolled loop -> pure renaming)
        if (kc + 1 < NC) {
            if constexpr (A_F32) {
                c0a = n0a; c0b = n0b; c1a = n1a; c1b = n1b;
            } else {
                cb0 = nb0; cb1 = nb1;
            }
        }
    }

#pragma unroll
    for (int rp = 0; rp < 2; ++rp) {
        const int crow0 = rowbase + rp * 16 + quad * 4;
#pragma unroll
        for (int t = 0; t < TILES; ++t) {
#pragma unroll
            for (int r = 0; r < 4; ++r) {
                const int rr = crow0 + r;
                if (rr < n)
                    C[(size_t)rr * M + t * 16 + l15] =
                        f32_to_bf16(acc[rp][t][r]);
            }
        }
    }
}

// ------------- per-node attention coefficients a_src, a_dst ---------------
template <int H, int C>
__global__ void att_kernel(const ushort_t* __restrict__ h,
                           const float* __restrict__ att_s,
                           const float* __restrict__ att_d,
                           float* __restrict__ as_, float* __restrict__ ad_,
                           int n) {
    const int idx = blockIdx.x * blockDim.x + threadIdx.x;
    if (idx >= n * H) return;
    const int node = idx / H;
    const int hh = idx % H;
    const ushort_t* hp = h + (size_t)node * H * C + hh * C;
    float s0 = 0.f, s1 = 0.f;
#pragma unroll
    for (int c = 0; c < C; ++c) {
        const float v = bf16_to_f32(hp[c]);
        s0 += v * att_s[hh * C + c];
        s1 += v * att_d[hh * C + c];
    }
    as_[idx] = s0;
    ad_[idx] = s1;
}

// ------------------- CSR build via binned counting sort -------------------
__global__ __launch_bounds__(1024) void hist_kernel(const int* __restrict__ dst,
                                                    int* __restrict__ histG,
                                                    int e, int chunk, int NB,
                                                    int G) {
    __shared__ int hl[512];
    for (int b = threadIdx.x; b < NB; b += 1024) hl[b] = 0;
    __syncthreads();
    const int g = blockIdx.x;
    const int lo = g * chunk;
    const int hi = min(lo + chunk, e);
    for (int i = lo + threadIdx.x; i < hi; i += 1024)
        atomicAdd(&hl[dst[i] >> 8], 1);
    __syncthreads();
    for (int b = threadIdx.x; b < NB; b += 1024) histG[b * G + g] = hl[b];
}

__global__ __launch_bounds__(1024) void scan1_kernel(const int* __restrict__ in,
                                                     int* __restrict__ out,
                                                     int* __restrict__ sums,
                                                     int n) {
    __shared__ int s[1024];
    const int t = threadIdx.x;
    const int i = blockIdx.x * 1024 + t;
    const int v = (i < n) ? in[i] : 0;
    s[t] = v;
    __syncthreads();
    for (int d = 1; d < 1024; d <<= 1) {
        const int x = (t >= d) ? s[t - d] : 0;
        __syncthreads();
        s[t] += x;
        __syncthreads();
    }
    if (i < n) out[i] = s[t] - v;
    if (t == 1023) sums[blockIdx.x] = s[1023];
}

__global__ __launch_bounds__(128) void scan2_kernel(int* sums, int nb) {
    __shared__ int s[128];
    const int t = threadIdx.x;
    const int v = (t < nb) ? sums[t] : 0;
    s[t] = v;
    __syncthreads();
    for (int d = 1; d < 128; d <<= 1) {
        const int x = (t >= d) ? s[t - d] : 0;
        __syncthreads();
        s[t] += x;
        __syncthreads();
    }
    if (t < nb) sums[t] = s[t] - v;
}

__global__ __launch_bounds__(1024) void scan3_kernel(int* __restrict__ out,
                                                     const int* __restrict__ sums,
                                                     int n) {
    const int i = blockIdx.x * 1024 + threadIdx.x;
    if (i < n) out[i] += sums[blockIdx.x];
}

__global__ __launch_bounds__(1024) void bin_kernel(const int* __restrict__ src,
                                                   const int* __restrict__ dst,
                                                   const int* __restrict__ base,
                                                   int2* __restrict__ binned,
                                                   int e, int chunk, int NB,
                                                   int G) {
    __shared__ int cur[512];
    const int g = blockIdx.x;
    for (int b = threadIdx.x; b < NB; b += 1024) cur[b] = base[b * G + g];
    __syncthreads();
    const int lo = g * chunk;
    const int hi = min(lo + chunk, e);
    for (int i = lo + threadIdx.x; i < hi; i += 1024) {
        const int d = dst[i];
        const int p = atomicAdd(&cur[d >> 8], 1);
        binned[p] = make_int2(src[i], d);
    }
}

#define BUILD_CAP 6144
__global__ __launch_bounds__(256) void build_kernel(
    const int2* __restrict__ binned, const int* __restrict__ base,
    int* __restrict__ csr, int* __restrict__ deg, int* __restrict__ offs,
    int e, int n, int NB, int G) {
    __shared__ int2 ep[BUILD_CAP];
    __shared__ int degL[256];
    __shared__ int offL[256];
    __shared__ int curL[256];
    const int b = blockIdx.x;
    const int tid = threadIdx.x;
    const int start = base[b * G];
    const int end = (b == NB - 1) ? e : base[(b + 1) * G];
    const int cnt = end - start;
    const bool stage = (cnt <= BUILD_CAP);
    degL[tid] = 0;
    if (stage)
        for (int i = tid; i < cnt; i += 256) ep[i] = binned[start + i];
    __syncthreads();
    if (stage) {
        for (int i = tid; i < cnt; i += 256) atomicAdd(&degL[ep[i].y & 255], 1);
    } else {
        for (int i = tid; i < cnt; i += 256)
            atomicAdd(&degL[binned[start + i].y & 255], 1);
    }
    __syncthreads();
    const int v = degL[tid];
    offL[tid] = v;
    __syncthreads();
    for (int d = 1; d < 256; d <<= 1) {
        const int x = (tid >= d) ? offL[tid - d] : 0;
        __syncthreads();
        offL[tid] += x;
        __syncthreads();
    }
    const int excl = offL[tid] - v;
    curL[tid] = excl;
    const int node = (b << 8) + tid;
    if (node < n) {
        deg[node] = v;
        offs[node] = start + excl;
    }
    __syncthreads();
    if (stage) {
        for (int i = tid; i < cnt; i += 256) {
            const int p = atomicAdd(&curL[ep[i].y & 255], 1);
            csr[start + p] = ep[i].x;
        }
    } else {
        for (int i = tid; i < cnt; i += 256) {
            const int2 pr = binned[start + i];
            const int p = atomicAdd(&curL[pr.y & 255], 1);
            csr[start + p] = pr.x;
        }
    }
}

// --------- single-pass gather-aggregate + fused softmax denominator -------
template <int H, int C, bool DO_ELU, bool OUT_BF16>
__global__ __launch_bounds__(64) void agg_kernel(
    const ushort_t* __restrict__ h, const float* __restrict__ a_src,
    const float* __restrict__ a_dst, const int* __restrict__ csr,
    const int* __restrict__ offs, const int* __restrict__ deg,
    const float* __restrict__ bias, void* __restrict__ outv, int n) {
    constexpr int HC = H * C;
    constexpr int R = HC / 64;  // 2 (layer1) or 1 (layer2)
    constexpr int U = 8;        // edge chunk size
    const int dst = blockIdx.x;
    const int lane = threadIdx.x;
    const int start = offs[dst];
    const int d = deg[dst];
    const int myh = lane & (H - 1);
    const int ch0 = lane * R;
    const int hh = ch0 / C;
    const float advm = a_dst[dst * H + myh];
    float acc0 = 0.f, acc1 = 0.f;
    float L = 0.f;

    {
        float e = a_src[dst * H + myh] + advm;
        e = fmaxf(e, 0.2f * e);
        const float p = __expf(e);
        L += p;
        const float a = (H > 1) ? __shfl(p, hh) : p;
        const ushort_t* hp = h + (size_t)dst * HC + ch0;
        if (R == 2) {
            const uint_t v = *(const uint_t*)hp;
            acc0 += a * bf16_to_f32((ushort_t)(v & 0xffffu));
            acc1 += a * bf16_to_f32((ushort_t)(v >> 16));
        } else {
            acc0 += a * bf16_to_f32(hp[0]);
        }
    }

    int j = 0;
    for (; j + U <= d; j += U) {
        int s[U];
        float es[U];
        uint_t hv[U];
#pragma unroll
        for (int u = 0; u < U; ++u) s[u] = csr[start + j + u];
#pragma unroll
        for (int u = 0; u < U; ++u) es[u] = a_src[s[u] * H + myh];
#pragma unroll
        for (int u = 0; u < U; ++u) {
            const ushort_t* hp = h + (size_t)s[u] * HC + ch0;
            if (R == 2) hv[u] = *(const uint_t*)hp;
            else hv[u] = (uint_t)hp[0];
        }
#pragma unroll
        for (int u = 0; u < U; ++u) {
            float e = es[u] + advm;
            e = fmaxf(e, 0.2f * e);
            const float p = __expf(e);
            L += p;
            const float a = (H > 1) ? __shfl(p, hh) : p;
            if (R == 2) {
                acc0 += a * bf16_to_f32((ushort_t)(hv[u] & 0xffffu));
                acc1 += a * bf16_to_f32((ushort_t)(hv[u] >> 16));
            } else {
                acc0 += a * bf16_to_f32((ushort_t)hv[u]);
            }
        }
    }
    for (; j < d; ++j) {
        const int src = csr[start + j];
        float e = a_src[src * H + myh] + advm;
        e = fmaxf(e, 0.2f * e);
        const float p = __expf(e);
        L += p;
        const float a = (H > 1) ? __shfl(p, hh) : p;
        const ushort_t* hp = h + (size_t)src * HC + ch0;
        if (R == 2) {
            const uint_t v = *(const uint_t*)hp;
            acc0 += a * bf16_to_f32((ushort_t)(v & 0xffffu));
            acc1 += a * bf16_to_f32((ushort_t)(v >> 16));
        } else {
            acc0 += a * bf16_to_f32(hp[0]);
        }
    }

    const float Ld = (H > 1) ? __shfl(L, hh) : L;
    const float linv = 1.f / (Ld + 1e-16f);
    float r0 = acc0 * linv + bias[ch0];
    if (DO_ELU) r0 = (r0 > 0.f) ? r0 : (__expf(r0) - 1.f);
    if (R == 2) {
        float r1 = acc1 * linv + bias[ch0 + 1];
        if (DO_ELU) r1 = (r1 > 0.f) ? r1 : (__expf(r1) - 1.f);
        if (OUT_BF16) {
            const uint_t packed =
                (uint_t)f32_to_bf16(r0) | ((uint_t)f32_to_bf16(r1) << 16);
            *(uint_t*)((ushort_t*)outv + (size_t)dst * HC + ch0) = packed;
        } else {
            *(float2*)((float*)outv + (size_t)dst * HC + ch0) =
                make_float2(r0, r1);
        }
    } else {
        if (OUT_BF16)
            ((ushort_t*)outv)[(size_t)dst * HC + ch0] = f32_to_bf16(r0);
        else
            ((float*)outv)[(size_t)dst * HC + ch0] = r0;
    }
}

// --------------------------------------------------------------------------
extern "C" void kernel_launch(void* const* d_in, const int* in_sizes, int n_in,
                              void* d_out, int out_size, void* d_ws,
                              size_t ws_size, hipStream_t stream) {
    const float* x = (const float*)d_in[0];
    const int* ei = (const int*)d_in[1];
    const float* W1 = (const float*)d_in[2];
    const float* att_s1 = (const float*)d_in[3];
    const float* att_d1 = (const float*)d_in[4];
    const float* b1 = (const float*)d_in[5];
    const float* W2 = (const float*)d_in[6];
    const float* att_s2 = (const float*)d_in[7];
    const float* att_d2 = (const float*)d_in[8];
    const float* b2 = (const float*)d_in[9];

    const int N = in_sizes[0] / 256;  // 100000
    const int E = in_sizes[1] / 2;    // 1600000
    const int* srcp = ei;
    const int* dstp = ei + E;

    const int NB = (N + 255) >> 8;  // 391 buckets of 256 nodes
    const int G = 128;
    const int NBG = NB * G;
    const int chunk = (E + G - 1) / G;
    const int nbs = (NBG + 1023) / 1024;

    // workspace layout
    float* as1 = (float*)d_ws;           // N*4
    float* ad1 = as1 + (size_t)N * 4;    // N*4
    float* as2 = ad1 + (size_t)N * 4;    // N
    float* ad2 = as2 + N;                // N
    int* histG = (int*)(ad2 + N);        // NBG
    int* base = histG + NBG;             // NBG
    int* sums = base + NBG;              // 128
    int* deg = sums + 128;               // N
    int* offs = deg + N;                 // N
    int* csr = offs + N;                 // E
    int2* binned = (int2*)(csr + E);     // E pairs (dead after build)
    ushort_t* h1 = (ushort_t*)binned;    // N*128 bf16 (overlays binned)
    ushort_t* h2 = h1 + (size_t)N * 128; // N*64 bf16
    ushort_t* h1p = h2 + (size_t)N * 64; // N*128 bf16 (agg1 out, gemm2 A)
    ushort_t* W1T = h1p + (size_t)N * 128;  // 128*256
    ushort_t* W2T = W1T + 128 * 256;        // 64*128

    // ---- weight transpose + bf16 convert ----
    convT_kernel<<<(256 * 128 + 255) / 256, 256, 0, stream>>>(W1, W1T, 256, 128);
    convT_kernel<<<(128 * 64 + 255) / 256, 256, 0, stream>>>(W2, W2T, 128, 64);

    // ---- CSR build (binned counting sort, no global atomics) ----
    hist_kernel<<<G, 1024, 0, stream>>>(dstp, histG, E, chunk, NB, G);
    scan1_kernel<<<nbs, 1024, 0, stream>>>(histG, base, sums, NBG);
    scan2_kernel<<<1, 128, 0, stream>>>(sums, nbs);
    scan3_kernel<<<nbs, 1024, 0, stream>>>(base, sums, NBG);
    bin_kernel<<<G, 1024, 0, stream>>>(srcp, dstp, base, binned, E, chunk, NB,
                                       G);
    build_kernel<<<NB, 256, 0, stream>>>(binned, base, csr, deg, offs, E, N,
                                         NB, G);

    const int gblk = (N + 127) / 128;  // 782 (128 rows per block)

    // ---- layer 1 ----
    gemm_lds_kernel<8, true, 256><<<gblk, 256, 0, stream>>>(x, W1T, h1, N);
    att_kernel<4, 32><<<(N * 4 + 255) / 256, 256, 0, stream>>>(h1, att_s1,
                                                               att_d1, as1,
                                                               ad1, N);
    agg_kernel<4, 32, true, true><<<N, 64, 0, stream>>>(h1, as1, ad1, csr,
                                                        offs, deg, b1, h1p, N);

    // ---- layer 2 ----
    gemm_lds_kernel<4, false, 128><<<gblk, 256, 0, stream>>>(h1p, W2T, h2, N);
    att_kernel<1, 64><<<(N + 255) / 256, 256, 0, stream>>>(h2, att_s2, att_d2,
                                                           as2, ad2, N);
    agg_kernel<1, 64, false, false><<<N, 64, 0, stream>>>(h2, as2, ad2, csr,
                                                          offs, deg, b2, d_out,
                                                          N);
}